// Round 12
// baseline (2149.747 us; speedup 1.0000x reference)
//
#include <hip/hip_runtime.h>

#define B_ 64
#define T_ 2048
#define I_ 128
#define H_ 128
#define CHUNK 128
#define NCHUNK (T_ / CHUNK)

typedef float f32x4 __attribute__((ext_vector_type(4)));
typedef int   i32x4 __attribute__((ext_vector_type(4)));

// ---------------- Phase 1: xp = x @ W_xh^T + (b_xh + b_hh) ----------------
__global__ __launch_bounds__(256) void xp_gemm(
    const float* __restrict__ x, const float* __restrict__ Wxh,
    const float* __restrict__ bxh, const float* __restrict__ bhh,
    float* __restrict__ xp)
{
    __shared__ float ws[H_ * I_];
    const int tid = threadIdx.x;
    {
        const float4* src = (const float4*)Wxh;
        float4* dst = (float4*)ws;
        #pragma unroll
        for (int i = 0; i < (H_ * I_ / 4) / 256; ++i)
            dst[tid + i * 256] = src[tid + i * 256];
    }
    __syncthreads();

    const int r0 = (tid >> 4) * 8;
    const int c0 = (tid & 15) * 8;
    const float* xb = x + ((size_t)blockIdx.x * 128 + r0) * I_;
    const float* wb = ws + c0 * I_;

    float acc[8][8];
    #pragma unroll
    for (int i = 0; i < 8; ++i)
        #pragma unroll
        for (int j = 0; j < 8; ++j) acc[i][j] = 0.f;

    float4 xa[8], wa[8], xn[8], wn[8];
    #pragma unroll
    for (int i = 0; i < 8; ++i) xa[i] = *(const float4*)(xb + i * I_);
    #pragma unroll
    for (int j = 0; j < 8; ++j) wa[j] = *(const float4*)(wb + j * I_);

    for (int k4 = 0; k4 < 32; k4 += 2) {
        #pragma unroll
        for (int i = 0; i < 8; ++i) xn[i] = *(const float4*)(xb + i * I_ + k4 * 4 + 4);
        #pragma unroll
        for (int j = 0; j < 8; ++j) wn[j] = *(const float4*)(wb + j * I_ + k4 * 4 + 4);
        #pragma unroll
        for (int i = 0; i < 8; ++i)
            #pragma unroll
            for (int j = 0; j < 8; ++j) {
                acc[i][j] = fmaf(xa[i].x, wa[j].x, acc[i][j]);
                acc[i][j] = fmaf(xa[i].y, wa[j].y, acc[i][j]);
                acc[i][j] = fmaf(xa[i].z, wa[j].z, acc[i][j]);
                acc[i][j] = fmaf(xa[i].w, wa[j].w, acc[i][j]);
            }
        if (k4 + 2 < 32) {
            #pragma unroll
            for (int i = 0; i < 8; ++i) xa[i] = *(const float4*)(xb + i * I_ + k4 * 4 + 8);
            #pragma unroll
            for (int j = 0; j < 8; ++j) wa[j] = *(const float4*)(wb + j * I_ + k4 * 4 + 8);
        }
        #pragma unroll
        for (int i = 0; i < 8; ++i)
            #pragma unroll
            for (int j = 0; j < 8; ++j) {
                acc[i][j] = fmaf(xn[i].x, wn[j].x, acc[i][j]);
                acc[i][j] = fmaf(xn[i].y, wn[j].y, acc[i][j]);
                acc[i][j] = fmaf(xn[i].z, wn[j].z, acc[i][j]);
                acc[i][j] = fmaf(xn[i].w, wn[j].w, acc[i][j]);
            }
    }

    const float4 ba0 = *(const float4*)(bxh + c0);
    const float4 ba1 = *(const float4*)(bxh + c0 + 4);
    const float4 bb0 = *(const float4*)(bhh + c0);
    const float4 bb1 = *(const float4*)(bhh + c0 + 4);
    float* orow = xp + ((size_t)blockIdx.x * 128 + r0) * H_ + c0;
    #pragma unroll
    for (int i = 0; i < 8; ++i) {
        float4 o0, o1;
        o0.x = acc[i][0] + ba0.x + bb0.x; o0.y = acc[i][1] + ba0.y + bb0.y;
        o0.z = acc[i][2] + ba0.z + bb0.z; o0.w = acc[i][3] + ba0.w + bb0.w;
        o1.x = acc[i][4] + ba1.x + bb1.x; o1.y = acc[i][5] + ba1.y + bb1.y;
        o1.z = acc[i][6] + ba1.z + bb1.z; o1.w = acc[i][7] + ba1.w + bb1.w;
        *(float4*)(orow + i * H_) = o0;
        *(float4*)(orow + i * H_ + 4) = o1;
    }
}

// Stage one 128-step xp chunk (64 KB) into LDS, 64 lanes x 16 B x 64 iters.
__device__ __forceinline__ void stage_chunk64(const float* __restrict__ g,
                                              float* l, int ln)
{
    #pragma unroll
    for (int i = 0; i < 64; ++i) {
        const int off = i * 256;
        __builtin_amdgcn_global_load_lds(
            (const __attribute__((address_space(1))) unsigned int*)(g + off + ln * 4),
            (__attribute__((address_space(3))) unsigned int*)(l + off),
            16, 0, 0);
    }
}

__device__ __forceinline__ i32x4 pk8(const float* p) {
    const float4 u0 = *(const float4*)p;
    const float4 u1 = *(const float4*)(p + 4);
    i32x4 t;
    t.x = __builtin_bit_cast(int, __builtin_amdgcn_cvt_pkrtz(u0.x, u0.y));
    t.y = __builtin_bit_cast(int, __builtin_amdgcn_cvt_pkrtz(u0.z, u0.w));
    t.z = __builtin_bit_cast(int, __builtin_amdgcn_cvt_pkrtz(u1.x, u1.y));
    t.w = __builtin_bit_cast(int, __builtin_amdgcn_cvt_pkrtz(u1.z, u1.w));
    return t;
}

#define FOR8(M) M(0) M(1) M(2) M(3) M(4) M(5) M(6) M(7)

// ---- static W fragments (named, AGPR-resident), row-permuted by rho_m ----
// rho_m(i) = 32*(m>>1) + 8*(i>>2) + 4*(m&1) + (i&3): makes each lane's D
// outputs exactly the h rows its next-step B fragment must supply.
#define DECLW(m) i32x4 w##m##_0, w##m##_1, w##m##_2, w##m##_3;
#define LOADW(m) { \
    const float* wr_ = Whh + (size_t)(32*((m)>>1) + 8*(c15>>2) + 4*((m)&1) + (c15&3)) * H_ + 8*gp; \
    w##m##_0 = pk8(wr_);      w##m##_1 = pk8(wr_ + 32); \
    w##m##_2 = pk8(wr_ + 64); w##m##_3 = pk8(wr_ + 96); }
#define PINW(m) asm("" : "+a"(w##m##_0), "+a"(w##m##_1), "+a"(w##m##_2), "+a"(w##m##_3));

// 4 chained MFMAs (k-tiles) for row-tile m; A from AGPR, B/C/D in VGPRs.
#define MF4(P,m) \
  asm("v_mfma_f32_16x16x32_f16 %0, %1, %2, %0" : "+v"(P##m) : "a"(w##m##_0), "v"(B0)); \
  asm("v_mfma_f32_16x16x32_f16 %0, %1, %2, %0" : "+v"(P##m) : "a"(w##m##_1), "v"(B1)); \
  asm("v_mfma_f32_16x16x32_f16 %0, %1, %2, %0" : "+v"(P##m) : "a"(w##m##_2), "v"(B2)); \
  asm("v_mfma_f32_16x16x32_f16 %0, %1, %2, %0" : "+v"(P##m) : "a"(w##m##_3), "v"(B3));

// prefetch next step's xp fragments (8 broadcast ds_read_b128, 4 addr groups)
#define PREF8(P, pn) \
  P##0 = *(const f32x4*)((pn) + 0);   P##1 = *(const f32x4*)((pn) + 4); \
  P##2 = *(const f32x4*)((pn) + 32);  P##3 = *(const f32x4*)((pn) + 36); \
  P##4 = *(const f32x4*)((pn) + 64);  P##5 = *(const f32x4*)((pn) + 68); \
  P##6 = *(const f32x4*)((pn) + 96);  P##7 = *(const f32x4*)((pn) + 100);

#define TH(x) (1.f - 2.f * __builtin_amdgcn_rcpf(exp2f((x) * 2.8853900817779268f) + 1.f))
#define TANH4(P,m) { P##m.x = TH(P##m.x); P##m.y = TH(P##m.y); \
                     P##m.z = TH(P##m.z); P##m.w = TH(P##m.w); }

#define PKI(a,b) __builtin_bit_cast(int, __builtin_amdgcn_cvt_pkrtz((a),(b)))
// NOTE: space between the pasted digit and ".member" -- "0.x" would lex as one
// pp-number token and the paste P##0.x forms an invalid token (round-11 bug).
#define PACKB(P) \
  B0.x = PKI(P##0 .x, P##0 .y); B0.y = PKI(P##0 .z, P##0 .w); \
  B0.z = PKI(P##1 .x, P##1 .y); B0.w = PKI(P##1 .z, P##1 .w); \
  B1.x = PKI(P##2 .x, P##2 .y); B1.y = PKI(P##2 .z, P##2 .w); \
  B1.z = PKI(P##3 .x, P##3 .y); B1.w = PKI(P##3 .z, P##3 .w); \
  B2.x = PKI(P##4 .x, P##4 .y); B2.y = PKI(P##4 .z, P##4 .w); \
  B2.z = PKI(P##5 .x, P##5 .y); B2.w = PKI(P##5 .z, P##5 .w); \
  B3.x = PKI(P##6 .x, P##6 .y); B3.y = PKI(P##6 .z, P##6 .w); \
  B3.z = PKI(P##7 .x, P##7 .y); B3.w = PKI(P##7 .z, P##7 .w);

// write lane's owned pair (rows soff, soff+1): parity+3-level cndmask tree
#define SELST(P, dptr) { \
  const bool p1_ = (c15 & 1); \
  float a0_ = p1_?P##0 .z:P##0 .x, q0_ = p1_?P##0 .w:P##0 .y; \
  float a1_ = p1_?P##1 .z:P##1 .x, q1_ = p1_?P##1 .w:P##1 .y; \
  float a2_ = p1_?P##2 .z:P##2 .x, q2_ = p1_?P##2 .w:P##2 .y; \
  float a3_ = p1_?P##3 .z:P##3 .x, q3_ = p1_?P##3 .w:P##3 .y; \
  float a4_ = p1_?P##4 .z:P##4 .x, q4_ = p1_?P##4 .w:P##4 .y; \
  float a5_ = p1_?P##5 .z:P##5 .x, q5_ = p1_?P##5 .w:P##5 .y; \
  float a6_ = p1_?P##6 .z:P##6 .x, q6_ = p1_?P##6 .w:P##6 .y; \
  float a7_ = p1_?P##7 .z:P##7 .x, q7_ = p1_?P##7 .w:P##7 .y; \
  const bool p2_ = (c15 & 2); \
  float c0_ = p2_?a1_:a0_, d0_ = p2_?q1_:q0_; \
  float c1_ = p2_?a3_:a2_, d1_ = p2_?q3_:q2_; \
  float c2_ = p2_?a5_:a4_, d2_ = p2_?q5_:q4_; \
  float c3_ = p2_?a7_:a6_, d3_ = p2_?q7_:q6_; \
  const bool p4_ = (c15 & 4); \
  float e0_ = p4_?c1_:c0_, f0_ = p4_?d1_:d0_; \
  float e1_ = p4_?c3_:c2_, f1_ = p4_?d3_:d2_; \
  const bool p8_ = (c15 & 8); \
  *(float2*)(dptr) = make_float2(p8_?e1_:e0_, p8_?f1_:f0_); }

#define STEP(P, N, s) { \
  MF4(P,0) MF4(P,1) MF4(P,2) MF4(P,3) MF4(P,4) MF4(P,5) MF4(P,6) MF4(P,7) \
  const float* pn_ = xpl + ((((s)+1) >> 7) & 1) * (CHUNK*H_) + (((s)+1) & 127) * H_ + loff; \
  PREF8(N, pn_) \
  TANH4(P,0) TANH4(P,1) TANH4(P,2) TANH4(P,3) TANH4(P,4) TANH4(P,5) TANH4(P,6) TANH4(P,7) \
  PACKB(P) \
  SELST(P, hsq + (size_t)(s) * H_) }

// ---------------- Phase 2: scan, ONE WAVE per batch, zero-exchange ----------
// Recurrence is fully lane-local: W row-permutation (rho_m) aligns D outputs
// with next-step B fragments. No LDS h buffer, no barriers, no cross-lane ops.
// Each lane redundantly tanhs its 32 (16x-replicated) values -- pure VALU.
__global__ __launch_bounds__(64) void rnn_scan(
    const float* __restrict__ Whh,
    float* __restrict__ seq /* xp in, h_seq out */, float* __restrict__ hlast)
{
    __shared__ float xpl[2 * CHUNK * H_];   // 128 KB xp double buffer

    const int l   = threadIdx.x;            // 0..63
    const int b   = blockIdx.x;
    const int c15 = l & 15;
    const int gp  = l >> 4;
    const int loff = 8 * gp;                // lane part of fragment offset
    const int soff = 32 * (c15 >> 2) + 8 * gp + 4 * ((c15 >> 1) & 1) + 2 * (c15 & 1);

    FOR8(DECLW)
    FOR8(LOADW)
    FOR8(PINW)

    float* xp  = seq + (size_t)b * T_ * H_;
    float* hsq = xp + soff;                 // h_seq store base (lane offset folded)

    stage_chunk64(xp, xpl, l);              // prologue: chunk 0

    i32x4 B0 = {0,0,0,0}, B1 = {0,0,0,0}, B2 = {0,0,0,0}, B3 = {0,0,0,0}; // h=0
    f32x4 xa0, xa1, xa2, xa3, xa4, xa5, xa6, xa7;
    f32x4 xn0, xn1, xn2, xn3, xn4, xn5, xn6, xn7;

    int s = 0;
    for (int c = 0; c < NCHUNK; ++c) {
        asm volatile("s_waitcnt vmcnt(0)" ::: "memory");   // chunk-c data in LDS
        if (c + 1 < NCHUNK)
            stage_chunk64(xp + (size_t)(c + 1) * CHUNK * H_,
                          xpl + ((c + 1) & 1) * (CHUNK * H_), l);
        {   // re-issue first-step fragments of this chunk (prev prefetch was pre-wait)
            const float* p0_ = xpl + (c & 1) * (CHUNK * H_) + loff;
            PREF8(xa, p0_)
        }
        for (int tt = 0; tt < CHUNK; tt += 2) {
            STEP(xa, xn, s) ++s;
            STEP(xn, xa, s) ++s;
        }
    }
    // t = 2047 (odd) was computed into the xn set
    SELST(xn, hlast + b * H_ + soff)
}

extern "C" void kernel_launch(void* const* d_in, const int* in_sizes, int n_in,
                              void* d_out, int out_size, void* d_ws, size_t ws_size,
                              hipStream_t stream)
{
    const float* x   = (const float*)d_in[0];
    const float* Wxh = (const float*)d_in[1];
    const float* bxh = (const float*)d_in[2];
    const float* Whh = (const float*)d_in[3];
    const float* bhh = (const float*)d_in[4];
    float* out   = (float*)d_out;
    float* hlast = out + (size_t)B_ * T_ * H_;

    xp_gemm<<<(B_ * T_) / 128, 256, 0, stream>>>(x, Wxh, bxh, bhh, out);
    rnn_scan<<<B_, 64, 0, stream>>>(Whh, out, hlast);
}

// Round 13
// 989.667 us; speedup vs baseline: 2.1722x; 2.1722x over previous
//
#include <hip/hip_runtime.h>

#define B_ 64
#define T_ 2048
#define I_ 128
#define H_ 128
#define CHUNK 128
#define NCHUNK (T_ / CHUNK)

typedef float f32x4 __attribute__((ext_vector_type(4)));
typedef int   i32x4 __attribute__((ext_vector_type(4)));

// ---------------- Phase 1: xp = x @ W_xh^T + (b_xh + b_hh) ----------------
__global__ __launch_bounds__(256) void xp_gemm(
    const float* __restrict__ x, const float* __restrict__ Wxh,
    const float* __restrict__ bxh, const float* __restrict__ bhh,
    float* __restrict__ xp)
{
    __shared__ float ws[H_ * I_];
    const int tid = threadIdx.x;
    {
        const float4* src = (const float4*)Wxh;
        float4* dst = (float4*)ws;
        #pragma unroll
        for (int i = 0; i < (H_ * I_ / 4) / 256; ++i)
            dst[tid + i * 256] = src[tid + i * 256];
    }
    __syncthreads();

    const int r0 = (tid >> 4) * 8;
    const int c0 = (tid & 15) * 8;
    const float* xb = x + ((size_t)blockIdx.x * 128 + r0) * I_;
    const float* wb = ws + c0 * I_;

    float acc[8][8];
    #pragma unroll
    for (int i = 0; i < 8; ++i)
        #pragma unroll
        for (int j = 0; j < 8; ++j) acc[i][j] = 0.f;

    float4 xa[8], wa[8], xn[8], wn[8];
    #pragma unroll
    for (int i = 0; i < 8; ++i) xa[i] = *(const float4*)(xb + i * I_);
    #pragma unroll
    for (int j = 0; j < 8; ++j) wa[j] = *(const float4*)(wb + j * I_);

    for (int k4 = 0; k4 < 32; k4 += 2) {
        #pragma unroll
        for (int i = 0; i < 8; ++i) xn[i] = *(const float4*)(xb + i * I_ + k4 * 4 + 4);
        #pragma unroll
        for (int j = 0; j < 8; ++j) wn[j] = *(const float4*)(wb + j * I_ + k4 * 4 + 4);
        #pragma unroll
        for (int i = 0; i < 8; ++i)
            #pragma unroll
            for (int j = 0; j < 8; ++j) {
                acc[i][j] = fmaf(xa[i].x, wa[j].x, acc[i][j]);
                acc[i][j] = fmaf(xa[i].y, wa[j].y, acc[i][j]);
                acc[i][j] = fmaf(xa[i].z, wa[j].z, acc[i][j]);
                acc[i][j] = fmaf(xa[i].w, wa[j].w, acc[i][j]);
            }
        if (k4 + 2 < 32) {
            #pragma unroll
            for (int i = 0; i < 8; ++i) xa[i] = *(const float4*)(xb + i * I_ + k4 * 4 + 8);
            #pragma unroll
            for (int j = 0; j < 8; ++j) wa[j] = *(const float4*)(wb + j * I_ + k4 * 4 + 8);
        }
        #pragma unroll
        for (int i = 0; i < 8; ++i)
            #pragma unroll
            for (int j = 0; j < 8; ++j) {
                acc[i][j] = fmaf(xn[i].x, wn[j].x, acc[i][j]);
                acc[i][j] = fmaf(xn[i].y, wn[j].y, acc[i][j]);
                acc[i][j] = fmaf(xn[i].z, wn[j].z, acc[i][j]);
                acc[i][j] = fmaf(xn[i].w, wn[j].w, acc[i][j]);
            }
    }

    const float4 ba0 = *(const float4*)(bxh + c0);
    const float4 ba1 = *(const float4*)(bxh + c0 + 4);
    const float4 bb0 = *(const float4*)(bhh + c0);
    const float4 bb1 = *(const float4*)(bhh + c0 + 4);
    float* orow = xp + ((size_t)blockIdx.x * 128 + r0) * H_ + c0;
    #pragma unroll
    for (int i = 0; i < 8; ++i) {
        float4 o0, o1;
        o0.x = acc[i][0] + ba0.x + bb0.x; o0.y = acc[i][1] + ba0.y + bb0.y;
        o0.z = acc[i][2] + ba0.z + bb0.z; o0.w = acc[i][3] + ba0.w + bb0.w;
        o1.x = acc[i][4] + ba1.x + bb1.x; o1.y = acc[i][5] + ba1.y + bb1.y;
        o1.z = acc[i][6] + ba1.z + bb1.z; o1.w = acc[i][7] + ba1.w + bb1.w;
        *(float4*)(orow + i * H_) = o0;
        *(float4*)(orow + i * H_ + 4) = o1;
    }
}

// Stage one 128-step xp chunk (64 KB) into LDS, 64 lanes x 16 B x 64 iters.
__device__ __forceinline__ void stage_chunk64(const float* __restrict__ g,
                                              float* l, int ln)
{
    #pragma unroll
    for (int i = 0; i < 64; ++i) {
        const int off = i * 256;
        __builtin_amdgcn_global_load_lds(
            (const __attribute__((address_space(1))) unsigned int*)(g + off + ln * 4),
            (__attribute__((address_space(3))) unsigned int*)(l + off),
            16, 0, 0);
    }
}

__device__ __forceinline__ i32x4 pk8(const float* p) {
    const float4 u0 = *(const float4*)p;
    const float4 u1 = *(const float4*)(p + 4);
    i32x4 t;
    t.x = __builtin_bit_cast(int, __builtin_amdgcn_cvt_pkrtz(u0.x, u0.y));
    t.y = __builtin_bit_cast(int, __builtin_amdgcn_cvt_pkrtz(u0.z, u0.w));
    t.z = __builtin_bit_cast(int, __builtin_amdgcn_cvt_pkrtz(u1.x, u1.y));
    t.w = __builtin_bit_cast(int, __builtin_amdgcn_cvt_pkrtz(u1.z, u1.w));
    return t;
}

#define FOR8(M) M(0) M(1) M(2) M(3) M(4) M(5) M(6) M(7)

// ---- static W fragments (named, AGPR-resident), row-permuted by rho_m ----
// rho_m(i) = 32*(m>>1) + 8*(i>>2) + 4*(m&1) + (i&3)  [verified: R12 absmax pass]
// => lane(gp,c15) reg r of tile m holds y[32*(m>>1) + 8*gp + 4*(m&1) + r].
#define DECLW(m) i32x4 w##m##_0, w##m##_1, w##m##_2, w##m##_3;
#define LOADW(m) { \
    const float* wr_ = Whh + (size_t)(32*((m)>>1) + 8*(c15>>2) + 4*((m)&1) + (c15&3)) * H_ + 8*gp; \
    w##m##_0 = pk8(wr_);      w##m##_1 = pk8(wr_ + 32); \
    w##m##_2 = pk8(wr_ + 64); w##m##_3 = pk8(wr_ + 96); }
#define PINW(m) asm("" : "+a"(w##m##_0), "+a"(w##m##_1), "+a"(w##m##_2), "+a"(w##m##_3));

// 4-stage MFMA chains, grouped by B operand so the 8 chains pipeline.
#define ROW0(m) asm("v_mfma_f32_16x16x32_f16 %0, %1, %2, %3" : "=&v"(P##m) : "a"(w##m##_0), "v"(B0), "v"(ZQ));
#define ROW1(m) asm("v_mfma_f32_16x16x32_f16 %0, %1, %2, %0" : "+v"(P##m) : "a"(w##m##_1), "v"(B1));
#define ROW2(m) asm("v_mfma_f32_16x16x32_f16 %0, %1, %2, %0" : "+v"(P##m) : "a"(w##m##_2), "v"(B2));
#define ROW3(m) asm("v_mfma_f32_16x16x32_f16 %0, %1, %2, %0" : "+v"(P##m) : "a"(w##m##_3), "v"(B3));

// owned-pair extract: quad m = c15>>1, regs (.x,.y) if c15 even else (.z,.w)
#define SEL1(m) const float s0_##m = po ? P##m .z : P##m .x, \
                            s1_##m = po ? P##m .w : P##m .y;

#define TH(x) (1.f - 2.f * __builtin_amdgcn_rcpf(exp2f((x) * 2.8853900817779268f) + 1.f))
#define BPERM(s) __builtin_amdgcn_ds_bpermute(ba##s, hp)
#define DECLBA(s) int ba##s;
#define INITBA(s) ba##s = ((l & 48) | (s)) << 2;
#define FOR16(M) M(0) M(1) M(2) M(3) M(4) M(5) M(6) M(7) \
                 M(8) M(9) M(10) M(11) M(12) M(13) M(14) M(15)

// ---------------- Phase 2: scan, ONE WAVE per batch, MFMA + bpermute --------
// Per step: 32 asm MFMA (A=W from AGPR, C=zero) -> select own pair (30 cnd)
// -> +xp pair -> 2 tanh (only 2 trans pairs/lane, vs R12's 32 = the 512cyc bug)
// -> pack 1 dword -> 16 ds_bpermute rebuild B quads. No LDS h buffer, no
// barriers, no cross-wave traffic. xp pair prefetched one step ahead from the
// LDS-staged chunk.
__global__ __launch_bounds__(64) void rnn_scan(
    const float* __restrict__ Whh,
    float* __restrict__ seq /* xp in, h_seq out */, float* __restrict__ hlast)
{
    __shared__ float xpl[2 * CHUNK * H_];   // 128 KB xp double buffer

    const int l   = threadIdx.x;            // 0..63
    const int b   = blockIdx.x;
    const int c15 = l & 15;
    const int gp  = l >> 4;
    // owned output rows (soff, soff+1); bijective over the 64 lanes
    const int soff = 32 * (c15 >> 2) + 8 * gp + 2 * (c15 & 3);

    FOR8(DECLW)
    FOR8(LOADW)
    FOR8(PINW)

    FOR16(DECLBA)
    FOR16(INITBA)

    f32x4 ZQ = {0.f, 0.f, 0.f, 0.f};
    asm("" : "+v"(ZQ));

    const bool po = c15 & 1;
    const bool m0 = (c15 >> 1) & 1, m1 = (c15 >> 2) & 1, m2 = (c15 >> 3) & 1;

    float* xp = seq + (size_t)b * T_ * H_;
    stage_chunk64(xp, xpl, l);              // prologue: chunk 0

    i32x4 B0 = {0,0,0,0}, B1 = {0,0,0,0}, B2 = {0,0,0,0}, B3 = {0,0,0,0}; // h=0
    float h0 = 0.f, h1 = 0.f;
    float2 xq;

    for (int c = 0; c < NCHUNK; ++c) {
        asm volatile("s_waitcnt vmcnt(0)" ::: "memory");   // chunk-c data in LDS
        if (c + 1 < NCHUNK)
            stage_chunk64(xp + (size_t)(c + 1) * CHUNK * H_,
                          xpl + ((c + 1) & 1) * (CHUNK * H_), l);

        const float* xb = xpl + (c & 1) * (CHUNK * H_);
        float* sq = xp + (size_t)c * CHUNK * H_;
        xq = *(const float2*)(xb + soff);   // t=0 pair of this chunk

        for (int t = 0; t < CHUNK; ++t) {
            f32x4 P0, P1, P2, P3, P4, P5, P6, P7;
            FOR8(ROW0) FOR8(ROW1) FOR8(ROW2) FOR8(ROW3)    // 32 MFMA
            SEL1(0) SEL1(1) SEL1(2) SEL1(3) SEL1(4) SEL1(5) SEL1(6) SEL1(7)
            const float t00 = m0 ? s0_1 : s0_0, t01 = m0 ? s0_3 : s0_2;
            const float t02 = m0 ? s0_5 : s0_4, t03 = m0 ? s0_7 : s0_6;
            const float t10 = m0 ? s1_1 : s1_0, t11 = m0 ? s1_3 : s1_2;
            const float t12 = m0 ? s1_5 : s1_4, t13 = m0 ? s1_7 : s1_6;
            const float u00 = m1 ? t01 : t00, u01 = m1 ? t03 : t02;
            const float u10 = m1 ? t11 : t10, u11 = m1 ? t13 : t12;
            const float y0 = m2 ? u01 : u00, y1 = m2 ? u11 : u10;
            const float p0 = y0 + xq.x;
            const float p1 = y1 + xq.y;
            // prefetch next step's xp pair (dead value at t=127; chunk head reloads)
            xq = *(const float2*)(xb + (size_t)((t + 1) & 127) * H_ + soff);
            h0 = TH(p0);
            h1 = TH(p1);
            const int hp = __builtin_bit_cast(int, __builtin_amdgcn_cvt_pkrtz(h0, h1));
            // rebuild B quads: B[q] word j <- lane (gp,4q+j)'s packed pair
            B0.x = BPERM(0);  B0.y = BPERM(1);  B0.z = BPERM(2);  B0.w = BPERM(3);
            B1.x = BPERM(4);  B1.y = BPERM(5);  B1.z = BPERM(6);  B1.w = BPERM(7);
            B2.x = BPERM(8);  B2.y = BPERM(9);  B2.z = BPERM(10); B2.w = BPERM(11);
            B3.x = BPERM(12); B3.y = BPERM(13); B3.z = BPERM(14); B3.w = BPERM(15);
            // h_seq store (queued global, off the recurrence path)
            *(float2*)(sq + (size_t)t * H_ + soff) = make_float2(h0, h1);
        }
    }
    *(float2*)&hlast[b * H_ + soff] = make_float2(h0, h1);
}

extern "C" void kernel_launch(void* const* d_in, const int* in_sizes, int n_in,
                              void* d_out, int out_size, void* d_ws, size_t ws_size,
                              hipStream_t stream)
{
    const float* x   = (const float*)d_in[0];
    const float* Wxh = (const float*)d_in[1];
    const float* bxh = (const float*)d_in[2];
    const float* Whh = (const float*)d_in[3];
    const float* bhh = (const float*)d_in[4];
    float* out   = (float*)d_out;
    float* hlast = out + (size_t)B_ * T_ * H_;

    xp_gemm<<<(B_ * T_) / 128, 256, 0, stream>>>(x, Wxh, bxh, bhh, out);
    rnn_scan<<<B_, 64, 0, stream>>>(Whh, out, hlast);
}